// Round 7
// baseline (363.250 us; speedup 1.0000x reference)
//
#include <hip/hip_runtime.h>
#include <cstdint>
#include <cstddef>

#define TT    4096          // sequence length
#define NB    4             // batch
#define DIMV  1024
#define MTOT  (NB*TT)       // 16384 rows
#define KK    1024          // GEMM K
#define NCOL  4096          // GEMM N (4*DIM)
#define NCH   64            // scan chunks
#define CL    (TT/NCH)      // 64 steps per chunk

#define BM 256
#define BN 256
#define BK 32

typedef _Float16 half8 __attribute__((ext_vector_type(8)));
typedef float    f32x4 __attribute__((ext_vector_type(4)));
typedef __attribute__((address_space(1))) void GV;
typedef __attribute__((address_space(3))) void LV;

__device__ __forceinline__ void gload16(const void* g, void* l) {
    __builtin_amdgcn_global_load_lds((GV*)g, (LV*)l, 16, 0, 0);
}

// fast activations: v_exp_f32 / v_log_f32 based, overflow-safe
__device__ __forceinline__ float ftanh(float x) {          // 1 - 2/(e^2x+1)
    return 1.0f - 2.0f / (__expf(2.0f * x) + 1.0f);
}
__device__ __forceinline__ float fsig(float x) {
    return 1.0f / (1.0f + __expf(-x));
}
__device__ __forceinline__ float fsoftplus(float x) {
    return fmaxf(x, 0.0f) + __logf(1.0f + __expf(-fabsf(x)));
}

// ---------- conversions ----------
__global__ __launch_bounds__(256) void k_cvt_x(const float* __restrict__ x,
                                               _Float16* __restrict__ Xs) {
    int idx = blockIdx.x * 256 + threadIdx.x;   // [16384][1024]
    Xs[idx] = (_Float16)x[idx];
}

// W [1024][4096] fp32 -> Wt [4096][1024] fp16 (transposed, N-major for B^T GEMM)
__global__ __launch_bounds__(256) void k_cvt_w(const float* __restrict__ W,
                                               _Float16* __restrict__ Wt) {
    __shared__ float tile[32][33];
    int tx = threadIdx.x & 31, ty = threadIdx.x >> 5;   // 32 x 8
    int nb = blockIdx.x * 32, kb = blockIdx.y * 32;
#pragma unroll
    for (int j = 0; j < 32; j += 8)
        tile[ty + j][tx] = W[(size_t)(kb + ty + j) * NCOL + nb + tx];
    __syncthreads();
#pragma unroll
    for (int j = 0; j < 32; j += 8)
        Wt[(size_t)(nb + ty + j) * KK + kb + tx] = (_Float16)tile[tx][ty + j];
}

// ---------- GEMM + fused gate activations ----------
// A = Xs [16384][1024] f16, Bt = Wt [4096][1024] f16 (both row-major).
// 256x256 tile, BK=32, 8 waves (2M x 4N), wave-tile 128x64 (8x4 frags of
// 16x16x32). TRIPLE-BUFFERED distance-2 prefetch with COUNTED vmcnt (T4):
// per K-tile phase = { vmcnt(4); s_barrier; sched_barrier; stage tile t+2;
// 32 MFMA }. Loads for tile t+1 (4/wave) stay in flight across the barrier —
// never drained to 0 inside the loop. Buffer (t+2)%3 holds tile t-1, whose
// reads finished before this barrier -> WAR-safe. Anti-conflict swizzle
// (rule 21): phys 16B slot s of row r holds logical slot s ^ ((r>>1)&3).
__global__ __launch_bounds__(512) void k_gemm_gates(
    const _Float16* __restrict__ Xs, const _Float16* __restrict__ Wt,
    const float* __restrict__ bias, const float* __restrict__ ibias,
    _Float16* __restrict__ gi, float* __restrict__ gf,
    _Float16* __restrict__ go, _Float16* __restrict__ gtz)
{
    __shared__ __align__(16) _Float16 Al0[BM * BK];   // 16 KB each, 96 KB total
    __shared__ __align__(16) _Float16 Al1[BM * BK];
    __shared__ __align__(16) _Float16 Al2[BM * BK];
    __shared__ __align__(16) _Float16 Bl0[BN * BK];
    __shared__ __align__(16) _Float16 Bl1[BN * BK];
    __shared__ __align__(16) _Float16 Bl2[BN * BK];
    const int tid  = threadIdx.x;       // 0..511
    const int lane = tid & 63;
    const int wave = tid >> 6;          // 0..7

    // bijective XCD swizzle (nwg = 1024, multiple of 8)
    const int nwg = 16 * 64;
    int id = blockIdx.y * 16 + blockIdx.x;
    id = (id & 7) * (nwg >> 3) + (id >> 3);
    const int m0 = (id / 16) * BM;
    const int n0 = (id % 16) * BN;
    const int wm = (wave >> 2) * 128;   // 0 | 128
    const int wn = (wave & 3) * 64;     // 0,64,128,192

    // staging: thread stages rows r0 and r0+128 (16B chunks), phys slot tid&3.
    const int r0  = tid >> 2;                        // 0..127
    const int swz = (tid & 3) ^ ((r0 >> 1) & 3);     // same for r0+128
    const _Float16* aSrc = Xs + (size_t)(m0 + r0) * KK + swz * 8;
    const _Float16* bSrc = Wt + (size_t)(n0 + r0) * KK + swz * 8;

    f32x4 acc[8][4] = {};
    const int lr = lane & 15;
    const int ps = ((lane >> 4) ^ ((lr >> 1) & 3)) * 8;   // phys slot on read

#define STAGE(SRC, BUF, kkc)                                              \
    gload16(SRC + (kkc), &BUF[tid * 8]);                                  \
    gload16(SRC + (size_t)128 * KK + (kkc), &BUF[tid * 8 + 4096]);

#define COMPUTE(ABUF, BBUF)                                               \
    {                                                                     \
        half8 af[8], bf[4];                                               \
        _Pragma("unroll")                                                 \
        for (int mi = 0; mi < 8; ++mi)                                    \
            af[mi] = *(const half8*)&ABUF[(wm + mi * 16 + lr) * BK + ps]; \
        _Pragma("unroll")                                                 \
        for (int nj = 0; nj < 4; ++nj)                                    \
            bf[nj] = *(const half8*)&BBUF[(wn + nj * 16 + lr) * BK + ps]; \
        __builtin_amdgcn_s_setprio(1);                                    \
        _Pragma("unroll")                                                 \
        for (int mi = 0; mi < 8; ++mi)                                    \
            _Pragma("unroll")                                             \
            for (int nj = 0; nj < 4; ++nj)                                \
                acc[mi][nj] = __builtin_amdgcn_mfma_f32_16x16x32_f16(     \
                    af[mi], bf[nj], acc[mi][nj], 0, 0, 0);                \
        __builtin_amdgcn_s_setprio(0);                                    \
    }

// counted-vmcnt phase: tile t+1's 4 loads/wave stay in flight across barrier
#define PHASE(CA, CB, NA, NB, kkn)                                        \
    asm volatile("s_waitcnt vmcnt(4)" ::: "memory");                      \
    __builtin_amdgcn_s_barrier();                                         \
    __builtin_amdgcn_sched_barrier(0);                                    \
    STAGE(aSrc, NA, kkn) STAGE(bSrc, NB, kkn)                             \
    COMPUTE(CA, CB)

    // prologue: stage tiles 0,1 into bufs 0,1 (8 loads/wave in flight)
    STAGE(aSrc, Al0, 0)  STAGE(bSrc, Bl0, 0)
    STAGE(aSrc, Al1, BK) STAGE(bSrc, Bl1, BK)

#pragma unroll 1
    for (int t3 = 0; t3 < 30; t3 += 3) {
        const int kk2 = (t3 + 2) * BK, kk3 = (t3 + 3) * BK, kk4 = (t3 + 4) * BK;
        PHASE(Al0, Bl0, Al2, Bl2, kk2)    // compute t3,   stage t3+2
        PHASE(Al1, Bl1, Al0, Bl0, kk3)    // compute t3+1, stage t3+3
        PHASE(Al2, Bl2, Al1, Bl1, kk4)    // compute t3+2, stage t3+4
    }
    // epilogue: tiles 30 (buf0), 31 (buf1); only terminal vmcnt(0)
    asm volatile("s_waitcnt vmcnt(4)" ::: "memory");
    __builtin_amdgcn_s_barrier();
    __builtin_amdgcn_sched_barrier(0);
    COMPUTE(Al0, Bl0)
    asm volatile("s_waitcnt vmcnt(0)" ::: "memory");
    __builtin_amdgcn_s_barrier();
    __builtin_amdgcn_sched_barrier(0);
    COMPUTE(Al1, Bl1)
#undef STAGE
#undef COMPUTE
#undef PHASE

    // epilogue: C/D layout col=lane&15, row=(lane>>4)*4+reg  [m89-verified]
    const int gate = n0 >> 10;          // block-uniform (256 | 1024)
#pragma unroll
    for (int mi = 0; mi < 8; ++mi) {
        const int rowb = m0 + wm + mi * 16 + (lane >> 4) * 4;
#pragma unroll
        for (int nj = 0; nj < 4; ++nj) {
            const int col = n0 + wn + nj * 16 + lr;
            const int d   = col & 1023;
            const float bb = bias[col];
#pragma unroll
            for (int r = 0; r < 4; ++r) {
                float v = acc[mi][nj][r] + bb;
                const int idx = (rowb + r) * DIMV + d;
                if (gate == 0) {
                    gi[idx] = (_Float16)(10.0f * ftanh((v + ibias[d]) * 0.1f));
                } else if (gate == 1) {
                    gf[idx] = -fsoftplus(v);                           // log-forget
                } else if (gate == 2) {
                    go[idx] = (_Float16)fsig(v);                       // sigmoid
                } else {
                    gtz[idx] = (_Float16)ftanh(v);                     // tanh(z)
                }
            }
        }
    }
}

// ---------- chunked scan ----------
// pass1: per (channel, chunk) local scan from identity (m=-1e30): {F=sum f, M, c, n}
__global__ __launch_bounds__(256) void k_scan1(
    const _Float16* __restrict__ gi, const float* __restrict__ gf,
    const _Float16* __restrict__ gtz, float4* __restrict__ sums)
{
    const int ch = blockIdx.x * 256 + threadIdx.x;   // 0..4095
    const int chunk = blockIdx.y;
    const int b = ch >> 10, d = ch & 1023;
    int base = (b * TT + chunk * CL) * DIMV + d;
    float m = -1e30f, c = 0.0f, n = 0.0f, F = 0.0f;
#pragma unroll 4
    for (int t = 0; t < CL; ++t, base += DIMV) {
        const float iv = (float)gi[base];
        const float fv = gf[base];
        const float zv = (float)gtz[base];
        F += fv;
        const float mn = fmaxf(fv + m, iv);
        const float sc = __expf(fv + m - mn);
        const float si = __expf(iv - mn);
        c = sc * c + si * zv;
        n = sc * n + si;
        m = mn;
    }
    sums[chunk * 4096 + ch] = make_float4(F, m, c, n);
}

// pass2: sequential combine over chunks; emit incoming state per chunk
__global__ __launch_bounds__(256) void k_scan2(const float4* __restrict__ sums,
                                               float4* __restrict__ states) {
    const int ch = blockIdx.x * 256 + threadIdx.x;
    float m = -1e30f, c = 0.0f, n = 0.0f;
    for (int chunk = 0; chunk < NCH; ++chunk) {
        states[chunk * 4096 + ch] = make_float4(m, c, n, 0.0f);
        const float4 s = sums[chunk * 4096 + ch];
        const float mn = fmaxf(m + s.x, s.y);
        const float e1 = __expf(m + s.x - mn);
        const float e2 = __expf(s.y - mn);
        c = e1 * c + e2 * s.z;
        n = e1 * n + e2 * s.w;
        m = mn;
    }
}

// pass3 + RMSNorm fused: block = (batch b, chunk). 256 threads own 4 channels
// each; block-reduce sum h^2 per timestep; write normalized fp32 out directly.
__global__ __launch_bounds__(256) void k_scan3norm(
    const _Float16* __restrict__ gi, const float* __restrict__ gf,
    const _Float16* __restrict__ go, const _Float16* __restrict__ gtz,
    const float4* __restrict__ states, const float* __restrict__ scale,
    float* __restrict__ out)
{
    const int b = blockIdx.x;           // 0..3
    const int chunk = blockIdx.y;       // 0..63
    const int d0 = threadIdx.x;         // 0..255
    const int wid = threadIdx.x >> 6, lane = threadIdx.x & 63;
    __shared__ float red[2][4];

    float m[4], c[4], n[4], sv[4];
#pragma unroll
    for (int j = 0; j < 4; ++j) {
        const float4 st = states[chunk * 4096 + b * 1024 + d0 + j * 256];
        m[j] = st.x; c[j] = st.y; n[j] = st.z;
        sv[j] = scale[d0 + j * 256];
    }
    int base = (b * TT + chunk * CL) * DIMV + d0;
    for (int t = 0; t < CL; ++t, base += DIMV) {
        float h[4];
        float part = 0.0f;
#pragma unroll
        for (int j = 0; j < 4; ++j) {
            const int idx = base + j * 256;
            const float iv = (float)gi[idx];
            const float fv = gf[idx];
            const float ov = (float)go[idx];
            const float zv = (float)gtz[idx];
            const float mn = fmaxf(fv + m[j], iv);
            const float sc = __expf(fv + m[j] - mn);
            const float si = __expf(iv - mn);
            c[j] = sc * c[j] + si * zv;
            n[j] = sc * n[j] + si;
            m[j] = mn;
            h[j] = ov * c[j] / (n[j] + 1e-6f);
            part += h[j] * h[j];
        }
#pragma unroll
        for (int off = 32; off > 0; off >>= 1) part += __shfl_xor(part, off, 64);
        if (lane == 0) red[t & 1][wid] = part;
        __syncthreads();
        const float tot = red[t & 1][0] + red[t & 1][1] + red[t & 1][2] + red[t & 1][3];
        const float inv = rsqrtf(tot * (1.0f / 1024.0f) + 1e-8f);
#pragma unroll
        for (int j = 0; j < 4; ++j)
            out[base + j * 256] = h[j] * inv * sv[j];
    }
}

extern "C" void kernel_launch(void* const* d_in, const int* in_sizes, int n_in,
                              void* d_out, int out_size, void* d_ws, size_t ws_size,
                              hipStream_t stream) {
    (void)in_sizes; (void)n_in; (void)out_size; (void)ws_size;
    const float* x     = (const float*)d_in[0];
    const float* W     = (const float*)d_in[1];
    const float* bias  = (const float*)d_in[2];
    const float* ibias = (const float*)d_in[3];
    const float* scale = (const float*)d_in[4];
    float* out = (float*)d_out;

    char* ws = (char*)d_ws;
    size_t off = 0;
    _Float16* Xs = (_Float16*)(ws + off); off += (size_t)MTOT * KK * 2;     //  33.5 MB
    _Float16* Wt = (_Float16*)(ws + off); off += (size_t)NCOL * KK * 2;     //   8.4 MB
    _Float16* gi = (_Float16*)(ws + off); off += (size_t)MTOT * DIMV * 2;   //  33.5 MB
    float*    gf = (float*)(ws + off);    off += (size_t)MTOT * DIMV * 4;   //  67.1 MB
    _Float16* go = (_Float16*)(ws + off); off += (size_t)MTOT * DIMV * 2;   //  33.5 MB
    _Float16* gtz= (_Float16*)(ws + off); off += (size_t)MTOT * DIMV * 2;   //  33.5 MB
    float4* sums   = (float4*)(ws + off); off += (size_t)NCH * 4096 * 16;   //   4.2 MB
    float4* states = (float4*)(ws + off); off += (size_t)NCH * 4096 * 16;   //   4.2 MB

    k_cvt_x<<<(MTOT * DIMV) / 256, 256, 0, stream>>>(x, Xs);
    k_cvt_w<<<dim3(NCOL / 32, KK / 32), 256, 0, stream>>>(W, Wt);
    k_gemm_gates<<<dim3(NCOL / BN, MTOT / BM), 512, 0, stream>>>(
        Xs, Wt, bias, ibias, gi, gf, go, gtz);
    k_scan1<<<dim3(16, NCH), 256, 0, stream>>>(gi, gf, gtz, sums);
    k_scan2<<<16, 256, 0, stream>>>(sums, states);
    k_scan3norm<<<dim3(NB, NCH), 256, 0, stream>>>(gi, gf, go, gtz, states, scale, out);
}

// Round 8
// 360.340 us; speedup vs baseline: 1.0081x; 1.0081x over previous
//
#include <hip/hip_runtime.h>
#include <cstdint>
#include <cstddef>

#define TT    4096          // sequence length
#define NB    4             // batch
#define DIMV  1024
#define MTOT  (NB*TT)       // 16384 rows
#define KK    1024          // GEMM K
#define NCOL  4096          // GEMM N (4*DIM)
#define NCH   64            // scan chunks
#define CL    (TT/NCH)      // 64 steps per chunk

#define BM 256
#define BN 256
#define BK 64

typedef _Float16 half8 __attribute__((ext_vector_type(8)));
typedef float    f32x4 __attribute__((ext_vector_type(4)));
typedef __attribute__((address_space(1))) void GV;
typedef __attribute__((address_space(3))) void LV;

__device__ __forceinline__ void gload16(const void* g, void* l) {
    __builtin_amdgcn_global_load_lds((GV*)g, (LV*)l, 16, 0, 0);
}

// fast activations: v_exp_f32 / v_log_f32 based, overflow-safe
__device__ __forceinline__ float ftanh(float x) {          // 1 - 2/(e^2x+1)
    return 1.0f - 2.0f / (__expf(2.0f * x) + 1.0f);
}
__device__ __forceinline__ float fsig(float x) {
    return 1.0f / (1.0f + __expf(-x));
}
__device__ __forceinline__ float fsoftplus(float x) {
    return fmaxf(x, 0.0f) + __logf(1.0f + __expf(-fabsf(x)));
}

// ---------- conversions ----------
__global__ __launch_bounds__(256) void k_cvt_x(const float* __restrict__ x,
                                               _Float16* __restrict__ Xs) {
    int idx = blockIdx.x * 256 + threadIdx.x;   // [16384][1024]
    Xs[idx] = (_Float16)x[idx];
}

// W [1024][4096] fp32 -> Wt [4096][1024] fp16 (transposed, N-major for B^T GEMM)
__global__ __launch_bounds__(256) void k_cvt_w(const float* __restrict__ W,
                                               _Float16* __restrict__ Wt) {
    __shared__ float tile[32][33];
    int tx = threadIdx.x & 31, ty = threadIdx.x >> 5;   // 32 x 8
    int nb = blockIdx.x * 32, kb = blockIdx.y * 32;
#pragma unroll
    for (int j = 0; j < 32; j += 8)
        tile[ty + j][tx] = W[(size_t)(kb + ty + j) * NCOL + nb + tx];
    __syncthreads();
#pragma unroll
    for (int j = 0; j < 32; j += 8)
        Wt[(size_t)(nb + ty + j) * KK + kb + tx] = (_Float16)tile[tx][ty + j];
}

// ---------- GEMM + fused gate activations (8-phase schedule, m201 skeleton) ----
// A = Xs [16384][1024] f16, Bt = Wt [4096][1024] f16 (both row-major).
// 256x256 tile, BK=64 (16 K-tiles), 8 waves (2M x 4N), wave-tile 128x64.
// Per K-tile: 4 phases, each {ds_read 4-8 b128 | stage 4 gloads (A@p0, B@p1) |
// barrier | lgkmcnt(0)+sched_barrier | setprio(1) 16 MFMA setprio(0) | barrier}.
// vmcnt(0) ONCE per K-tile at p3 (stage issued >=2 phases earlier).
// LDS: 2 x (A 32KB + B 32KB) = 128 KB, 1 block/CU.
// Rows are 128 B (= bank wrap): swizzle phys 16B slot s of row r holds logical
// slot s ^ (r&7) — linear LDS dest, pre-swizzled global src, XOR on read.
__global__ __launch_bounds__(512) void k_gemm_gates(
    const _Float16* __restrict__ Xs, const _Float16* __restrict__ Wt,
    const float* __restrict__ bias, const float* __restrict__ ibias,
    _Float16* __restrict__ gi, float* __restrict__ gf,
    _Float16* __restrict__ go, _Float16* __restrict__ gtz)
{
    __shared__ __align__(16) _Float16 Al0[BM * BK];   // 32 KB each
    __shared__ __align__(16) _Float16 Al1[BM * BK];
    __shared__ __align__(16) _Float16 Bl0[BN * BK];
    __shared__ __align__(16) _Float16 Bl1[BN * BK];
    const int tid  = threadIdx.x;       // 0..511
    const int lane = tid & 63;
    const int wave = tid >> 6;          // 0..7

    // bijective XCD swizzle (nwg = 1024, multiple of 8)
    const int nwg = 16 * 64;
    int id = blockIdx.y * 16 + blockIdx.x;
    id = (id & 7) * (nwg >> 3) + (id >> 3);
    const int m0 = (id / 16) * BM;
    const int n0 = (id % 16) * BN;
    const int wm = (wave >> 2) * 128;   // 0 | 128
    const int wn = (wave & 3) * 64;     // 0,64,128,192

    // staging: thread t stages chunks t, t+512, t+1024, t+1536 of a 256x64 tile
    // (chunk c -> row c>>3, phys slot c&7). Source col = swizzled logical slot.
    const int r0  = tid >> 3;                        // 0..63
    const int swc = ((tid & 7) ^ (r0 & 7)) * 8;      // same for r0+64k
    const _Float16* aSrc = Xs + (size_t)(m0 + r0) * KK + swc;
    const _Float16* bSrc = Wt + (size_t)(n0 + r0) * KK + swc;

    f32x4 acc[8][4] = {};
    const int lr = lane & 15;
    const int g  = lane >> 4;
    const int x7 = lr & 7;
    const int ps0 = ((g)     ^ x7) * 8;   // phys slot (f16 offset), k-slice 0
    const int ps1 = ((4 + g) ^ x7) * 8;   // k-slice 1

#define STAGE4(SRC, BUF, kkc)                                              \
    gload16(SRC + (kkc),                    &BUF[tid * 8]);                \
    gload16(SRC + (size_t) 64 * KK + (kkc), &BUF[tid * 8 + 4096]);         \
    gload16(SRC + (size_t)128 * KK + (kkc), &BUF[tid * 8 + 8192]);         \
    gload16(SRC + (size_t)192 * KK + (kkc), &BUF[tid * 8 + 12288]);

#define LDA(BUF, MI, PS) (*(const half8*)&BUF[(wm + (MI) * 16 + lr) * BK + (PS)])
#define LDB(BUF, NJ, PS) (*(const half8*)&BUF[(wn + (NJ) * 16 + lr) * BK + (PS)])

#define BARRIER __builtin_amdgcn_s_barrier()
#define LGKM0 do { asm volatile("s_waitcnt lgkmcnt(0)" ::: "memory");      \
                   __builtin_amdgcn_sched_barrier(0); } while (0)

#define Q16(AOFF)                                                          \
    __builtin_amdgcn_s_setprio(1);                                         \
    _Pragma("unroll")                                                      \
    for (int mi = 0; mi < 4; ++mi)                                         \
        _Pragma("unroll")                                                  \
        for (int nj = 0; nj < 4; ++nj)                                     \
            acc[(AOFF) + mi][nj] = __builtin_amdgcn_mfma_f32_16x16x32_f16( \
                av[mi], bv[nj], acc[(AOFF) + mi][nj], 0, 0, 0);            \
    __builtin_amdgcn_s_setprio(0);

// one K-tile = 4 phases; stages next tile's A in p0, B in p1; vmcnt(0) at p3.
#define KTILE(AB, BB, SA, SB, kkn, DOSTAGE)                                \
  {                                                                        \
    half8 av[4], bv[4];                                                    \
    av[0]=LDA(AB,0,ps0); av[1]=LDA(AB,1,ps0); av[2]=LDA(AB,2,ps0); av[3]=LDA(AB,3,ps0); \
    bv[0]=LDB(BB,0,ps0); bv[1]=LDB(BB,1,ps0); bv[2]=LDB(BB,2,ps0); bv[3]=LDB(BB,3,ps0); \
    if (DOSTAGE) { STAGE4(aSrc, SA, kkn) }                                 \
    BARRIER; LGKM0; Q16(0) BARRIER;                                        \
    av[0]=LDA(AB,4,ps0); av[1]=LDA(AB,5,ps0); av[2]=LDA(AB,6,ps0); av[3]=LDA(AB,7,ps0); \
    if (DOSTAGE) { STAGE4(bSrc, SB, kkn) }                                 \
    BARRIER; LGKM0; Q16(4) BARRIER;                                        \
    av[0]=LDA(AB,0,ps1); av[1]=LDA(AB,1,ps1); av[2]=LDA(AB,2,ps1); av[3]=LDA(AB,3,ps1); \
    bv[0]=LDB(BB,0,ps1); bv[1]=LDB(BB,1,ps1); bv[2]=LDB(BB,2,ps1); bv[3]=LDB(BB,3,ps1); \
    BARRIER; LGKM0; Q16(0) BARRIER;                                        \
    av[0]=LDA(AB,4,ps1); av[1]=LDA(AB,5,ps1); av[2]=LDA(AB,6,ps1); av[3]=LDA(AB,7,ps1); \
    BARRIER; LGKM0; Q16(4)                                                 \
    asm volatile("s_waitcnt vmcnt(0)" ::: "memory");                       \
    __builtin_amdgcn_sched_barrier(0);                                     \
    BARRIER;                                                               \
  }

    // prologue: tile 0 -> buf0, fully landed before first ds_read
    STAGE4(aSrc, Al0, 0) STAGE4(bSrc, Bl0, 0)
    asm volatile("s_waitcnt vmcnt(0)" ::: "memory");
    BARRIER;

#pragma unroll 1
    for (int tt = 0; tt < 8; ++tt) {
        const int k1 = (2 * tt + 1) * BK, k2 = (2 * tt + 2) * BK;
        KTILE(Al0, Bl0, Al1, Bl1, k1, true)       // tile 2tt,   stage 2tt+1
        KTILE(Al1, Bl1, Al0, Bl0, k2, (tt < 7))   // tile 2tt+1, stage 2tt+2
    }
#undef STAGE4
#undef LDA
#undef LDB
#undef Q16
#undef KTILE

    // epilogue: C/D layout col=lane&15, row=(lane>>4)*4+reg  [m89-verified]
    const int gate = n0 >> 10;          // block-uniform (256 | 1024)
#pragma unroll
    for (int mi = 0; mi < 8; ++mi) {
        const int rowb = m0 + wm + mi * 16 + (lane >> 4) * 4;
#pragma unroll
        for (int nj = 0; nj < 4; ++nj) {
            const int col = n0 + wn + nj * 16 + lr;
            const int d   = col & 1023;
            const float bb = bias[col];
#pragma unroll
            for (int r = 0; r < 4; ++r) {
                float v = acc[mi][nj][r] + bb;
                const int idx = (rowb + r) * DIMV + d;
                if (gate == 0) {
                    gi[idx] = (_Float16)(10.0f * ftanh((v + ibias[d]) * 0.1f));
                } else if (gate == 1) {
                    gf[idx] = -fsoftplus(v);                           // log-forget
                } else if (gate == 2) {
                    go[idx] = (_Float16)fsig(v);                       // sigmoid
                } else {
                    gtz[idx] = (_Float16)ftanh(v);                     // tanh(z)
                }
            }
        }
    }
}

// ---------- chunked scan ----------
// pass1: per (channel, chunk) local scan from identity (m=-1e30): {F=sum f, M, c, n}
__global__ __launch_bounds__(256) void k_scan1(
    const _Float16* __restrict__ gi, const float* __restrict__ gf,
    const _Float16* __restrict__ gtz, float4* __restrict__ sums)
{
    const int ch = blockIdx.x * 256 + threadIdx.x;   // 0..4095
    const int chunk = blockIdx.y;
    const int b = ch >> 10, d = ch & 1023;
    int base = (b * TT + chunk * CL) * DIMV + d;
    float m = -1e30f, c = 0.0f, n = 0.0f, F = 0.0f;
#pragma unroll 4
    for (int t = 0; t < CL; ++t, base += DIMV) {
        const float iv = (float)gi[base];
        const float fv = gf[base];
        const float zv = (float)gtz[base];
        F += fv;
        const float mn = fmaxf(fv + m, iv);
        const float sc = __expf(fv + m - mn);
        const float si = __expf(iv - mn);
        c = sc * c + si * zv;
        n = sc * n + si;
        m = mn;
    }
    sums[chunk * 4096 + ch] = make_float4(F, m, c, n);
}

// pass2: sequential combine over chunks; emit incoming state per chunk
__global__ __launch_bounds__(256) void k_scan2(const float4* __restrict__ sums,
                                               float4* __restrict__ states) {
    const int ch = blockIdx.x * 256 + threadIdx.x;
    float m = -1e30f, c = 0.0f, n = 0.0f;
    for (int chunk = 0; chunk < NCH; ++chunk) {
        states[chunk * 4096 + ch] = make_float4(m, c, n, 0.0f);
        const float4 s = sums[chunk * 4096 + ch];
        const float mn = fmaxf(m + s.x, s.y);
        const float e1 = __expf(m + s.x - mn);
        const float e2 = __expf(s.y - mn);
        c = e1 * c + e2 * s.z;
        n = e1 * n + e2 * s.w;
        m = mn;
    }
}

// pass3: re-scan chunk from incoming state, emit h (fp16) into hbuf
__global__ __launch_bounds__(256) void k_scan3(
    const _Float16* __restrict__ gi, const float* __restrict__ gf,
    const _Float16* __restrict__ go, const _Float16* __restrict__ gtz,
    const float4* __restrict__ states, _Float16* __restrict__ hbuf)
{
    const int ch = blockIdx.x * 256 + threadIdx.x;
    const int chunk = blockIdx.y;
    const int b = ch >> 10, d = ch & 1023;
    int base = (b * TT + chunk * CL) * DIMV + d;
    const float4 st = states[chunk * 4096 + ch];
    float m = st.x, c = st.y, n = st.z;
#pragma unroll 4
    for (int t = 0; t < CL; ++t, base += DIMV) {
        const float iv = (float)gi[base];
        const float fv = gf[base];
        const float ov = (float)go[base];
        const float zv = (float)gtz[base];
        const float mn = fmaxf(fv + m, iv);
        const float sc = __expf(fv + m - mn);
        const float si = __expf(iv - mn);
        c = sc * c + si * zv;
        n = sc * n + si;
        m = mn;
        hbuf[base] = (_Float16)(ov * c / (n + 1e-6f));
    }
}

// ---------- RMSNorm: read h fp16, write fp32 out; one wave per 1024-row ----------
__global__ __launch_bounds__(256) void k_rmsnorm(const _Float16* __restrict__ h,
                                                 const float* __restrict__ scale,
                                                 float* __restrict__ out) {
    const int wid = threadIdx.x >> 6, lane = threadIdx.x & 63;
    const int row = blockIdx.x * 4 + wid;
    const half8* p = (const half8*)(h + (size_t)row * DIMV);  // 128 half8/row
    const float4* sc = (const float4*)scale;
    half8 v0 = p[lane * 2], v1 = p[lane * 2 + 1];             // 16 f16 per lane
    float f[16];
    float ss = 0.0f;
#pragma unroll
    for (int j = 0; j < 8; ++j) { f[j] = (float)v0[j]; f[8 + j] = (float)v1[j]; }
#pragma unroll
    for (int j = 0; j < 16; ++j) ss += f[j] * f[j];
#pragma unroll
    for (int off = 32; off > 0; off >>= 1) ss += __shfl_xor(ss, off, 64);
    const float inv = 1.0f / sqrtf(ss * (1.0f / 1024.0f) + 1e-8f);
    float4* po = (float4*)(out + (size_t)row * DIMV + lane * 16);
#pragma unroll
    for (int q = 0; q < 4; ++q) {
        const float4 s = sc[lane * 4 + q];
        float4 o;
        o.x = f[q * 4 + 0] * inv * s.x;
        o.y = f[q * 4 + 1] * inv * s.y;
        o.z = f[q * 4 + 2] * inv * s.z;
        o.w = f[q * 4 + 3] * inv * s.w;
        po[q] = o;
    }
}

extern "C" void kernel_launch(void* const* d_in, const int* in_sizes, int n_in,
                              void* d_out, int out_size, void* d_ws, size_t ws_size,
                              hipStream_t stream) {
    (void)in_sizes; (void)n_in; (void)out_size; (void)ws_size;
    const float* x     = (const float*)d_in[0];
    const float* W     = (const float*)d_in[1];
    const float* bias  = (const float*)d_in[2];
    const float* ibias = (const float*)d_in[3];
    const float* scale = (const float*)d_in[4];
    float* out = (float*)d_out;

    char* ws = (char*)d_ws;
    size_t off = 0;
    _Float16* Xs = (_Float16*)(ws + off); off += (size_t)MTOT * KK * 2;     //  33.5 MB
    _Float16* Wt = (_Float16*)(ws + off); off += (size_t)NCOL * KK * 2;     //   8.4 MB
    _Float16* gi = (_Float16*)(ws + off); off += (size_t)MTOT * DIMV * 2;   //  33.5 MB
    float*    gf = (float*)(ws + off);    off += (size_t)MTOT * DIMV * 4;   //  67.1 MB
    _Float16* go = (_Float16*)(ws + off); off += (size_t)MTOT * DIMV * 2;   //  33.5 MB
    _Float16* gtz= (_Float16*)(ws + off); off += (size_t)MTOT * DIMV * 2;   //  33.5 MB
    float4* sums   = (float4*)(ws + off); off += (size_t)NCH * 4096 * 16;   //   4.2 MB
    float4* states = (float4*)(ws + off); off += (size_t)NCH * 4096 * 16;   //   4.2 MB
    _Float16* hbuf = Xs;   // Xs is dead after the GEMM; reuse for h (33.5 MB)

    k_cvt_x<<<(MTOT * DIMV) / 256, 256, 0, stream>>>(x, Xs);
    k_cvt_w<<<dim3(NCOL / 32, KK / 32), 256, 0, stream>>>(W, Wt);
    k_gemm_gates<<<dim3(NCOL / BN, MTOT / BM), 512, 0, stream>>>(
        Xs, Wt, bias, ibias, gi, gf, go, gtz);
    k_scan1<<<dim3(16, NCH), 256, 0, stream>>>(gi, gf, gtz, sums);
    k_scan2<<<16, 256, 0, stream>>>(sums, states);
    k_scan3<<<dim3(16, NCH), 256, 0, stream>>>(gi, gf, go, gtz, states, hbuf);
    k_rmsnorm<<<MTOT / 4, 256, 0, stream>>>(hbuf, scale, out);
}

// Round 9
// 358.597 us; speedup vs baseline: 1.0130x; 1.0049x over previous
//
#include <hip/hip_runtime.h>
#include <cstdint>
#include <cstddef>

#define TT    4096          // sequence length
#define NB    4             // batch
#define DIMV  1024
#define MTOT  (NB*TT)       // 16384 rows
#define KK    1024          // GEMM K
#define NCOL  4096          // GEMM N (4*DIM)
#define NCH   64            // scan chunks
#define CL    (TT/NCH)      // 64 steps per chunk

#define BM 256
#define BN 256
#define BK 32

typedef _Float16 half8 __attribute__((ext_vector_type(8)));
typedef float    f32x4 __attribute__((ext_vector_type(4)));
typedef __attribute__((address_space(1))) void GV;
typedef __attribute__((address_space(3))) void LV;

__device__ __forceinline__ void gload16(const void* g, void* l) {
    __builtin_amdgcn_global_load_lds((GV*)g, (LV*)l, 16, 0, 0);
}

// fast activations: v_exp_f32 / v_log_f32 based, overflow-safe
__device__ __forceinline__ float ftanh(float x) {          // 1 - 2/(e^2x+1)
    return 1.0f - 2.0f / (__expf(2.0f * x) + 1.0f);
}
__device__ __forceinline__ float fsig(float x) {
    return 1.0f / (1.0f + __expf(-x));
}
__device__ __forceinline__ float fsoftplus(float x) {
    return fmaxf(x, 0.0f) + __logf(1.0f + __expf(-fabsf(x)));
}

// ---------- conversions ----------
__global__ __launch_bounds__(256) void k_cvt_x(const float* __restrict__ x,
                                               _Float16* __restrict__ Xs) {
    int idx = blockIdx.x * 256 + threadIdx.x;   // [16384][1024]
    Xs[idx] = (_Float16)x[idx];
}

// W [1024][4096] fp32 -> Wt [4096][1024] fp16 (transposed, N-major for B^T GEMM)
__global__ __launch_bounds__(256) void k_cvt_w(const float* __restrict__ W,
                                               _Float16* __restrict__ Wt) {
    __shared__ float tile[32][33];
    int tx = threadIdx.x & 31, ty = threadIdx.x >> 5;   // 32 x 8
    int nb = blockIdx.x * 32, kb = blockIdx.y * 32;
#pragma unroll
    for (int j = 0; j < 32; j += 8)
        tile[ty + j][tx] = W[(size_t)(kb + ty + j) * NCOL + nb + tx];
    __syncthreads();
#pragma unroll
    for (int j = 0; j < 32; j += 8)
        Wt[(size_t)(nb + ty + j) * KK + kb + tx] = (_Float16)tile[tx][ty + j];
}

// ---------- GEMM + fused gate activations ----------
// A = Xs [16384][1024] f16, Bt = Wt [4096][1024] f16 (both row-major).
// 256x256 tile, BK=32 (32 K-tiles), 8 waves (2M x 4N), wave-tile 128x64.
// FINE-INTERLEAVE + COUNTED VMCNT (T3+T4): triple-buffered (3 x 32 KB),
// distance-2 staging. Per K-tile = 2 phases:
//   {8 ds_read | stage A(T+2) | bar | lgkm0 | 16 MFMA | bar}
//   {4 ds_read | stage B(T+2) | bar | lgkm0 | 16 MFMA | vmcnt(4) | bar}
// vmcnt(4) keeps T+2's 4 loads in flight; T+1's (issued one full tile
// earlier) are forced complete by in-order retirement (m135). WAR: stage
// target buf[(T+2)%3] is T-1's buffer, vacated before the end-of-(T-1)
// barrier. Anti-conflict swizzle (rule 21, R6-proven 0 conflicts):
// phys 16B slot s of row r holds logical slot s ^ ((r>>1)&3).
__global__ __launch_bounds__(512) void k_gemm_gates(
    const _Float16* __restrict__ Xs, const _Float16* __restrict__ Wt,
    const float* __restrict__ bias, const float* __restrict__ ibias,
    _Float16* __restrict__ gi, float* __restrict__ gf,
    _Float16* __restrict__ go, _Float16* __restrict__ gtz)
{
    __shared__ __align__(16) _Float16 Al0[BM * BK];   // 16 KB each, 96 KB total
    __shared__ __align__(16) _Float16 Al1[BM * BK];
    __shared__ __align__(16) _Float16 Al2[BM * BK];
    __shared__ __align__(16) _Float16 Bl0[BN * BK];
    __shared__ __align__(16) _Float16 Bl1[BN * BK];
    __shared__ __align__(16) _Float16 Bl2[BN * BK];
    const int tid  = threadIdx.x;       // 0..511
    const int lane = tid & 63;
    const int wave = tid >> 6;          // 0..7

    // bijective XCD swizzle (nwg = 1024, multiple of 8)
    const int nwg = 16 * 64;
    int id = blockIdx.y * 16 + blockIdx.x;
    id = (id & 7) * (nwg >> 3) + (id >> 3);
    const int m0 = (id / 16) * BM;
    const int n0 = (id % 16) * BN;
    const int wm = (wave >> 2) * 128;   // 0 | 128
    const int wn = (wave & 3) * 64;     // 0,64,128,192

    // staging: thread stages rows r0 and r0+128 (16B chunks), phys slot tid&3.
    const int r0  = tid >> 2;                        // 0..127
    const int swz = (tid & 3) ^ ((r0 >> 1) & 3);     // same for r0+128
    const _Float16* aSrc = Xs + (size_t)(m0 + r0) * KK + swz * 8;
    const _Float16* bSrc = Wt + (size_t)(n0 + r0) * KK + swz * 8;

    f32x4 acc[8][4] = {};
    const int lr = lane & 15;
    const int ps = ((lane >> 4) ^ ((lr >> 1) & 3)) * 8;   // phys slot on read

#define STAGEA(BUF, kkc)                                                   \
    gload16(aSrc + (kkc), &BUF[tid * 8]);                                  \
    gload16(aSrc + (size_t)128 * KK + (kkc), &BUF[tid * 8 + 4096]);
#define STAGEB(BUF, kkc)                                                   \
    gload16(bSrc + (kkc), &BUF[tid * 8]);                                  \
    gload16(bSrc + (size_t)128 * KK + (kkc), &BUF[tid * 8 + 4096]);

#define LDA(BUF, MI) (*(const half8*)&BUF[(wm + (MI) * 16 + lr) * BK + ps])
#define LDB(BUF, NJ) (*(const half8*)&BUF[(wn + (NJ) * 16 + lr) * BK + ps])

#define BARRIER __builtin_amdgcn_s_barrier()
#define LGKM0 do { asm volatile("s_waitcnt lgkmcnt(0)" ::: "memory");      \
                   __builtin_amdgcn_sched_barrier(0); } while (0)

#define Q16(AOFF)                                                          \
    __builtin_amdgcn_s_setprio(1);                                         \
    _Pragma("unroll")                                                      \
    for (int mi = 0; mi < 4; ++mi)                                         \
        _Pragma("unroll")                                                  \
        for (int nj = 0; nj < 4; ++nj)                                     \
            acc[(AOFF) + mi][nj] = __builtin_amdgcn_mfma_f32_16x16x32_f16( \
                av[mi], bv[nj], acc[(AOFF) + mi][nj], 0, 0, 0);            \
    __builtin_amdgcn_s_setprio(0);

// one K-tile = 2 fine phases; stages tile T+2 (A in p0, B in p1); trailing
// counted vmcnt — never 0 in the main loop.
#define KTILE(AB, BB, SA, SB, kkn, DOSTAGE, EW, TRAIL)                     \
  {                                                                        \
    half8 av[4], bv[4];                                                    \
    av[0]=LDA(AB,0); av[1]=LDA(AB,1); av[2]=LDA(AB,2); av[3]=LDA(AB,3);    \
    bv[0]=LDB(BB,0); bv[1]=LDB(BB,1); bv[2]=LDB(BB,2); bv[3]=LDB(BB,3);    \
    if (DOSTAGE) { STAGEA(SA, kkn) }                                       \
    BARRIER; LGKM0; Q16(0) BARRIER;                                        \
    av[0]=LDA(AB,4); av[1]=LDA(AB,5); av[2]=LDA(AB,6); av[3]=LDA(AB,7);    \
    if (DOSTAGE) { STAGEB(SB, kkn) }                                       \
    BARRIER; LGKM0; Q16(4)                                                 \
    if (TRAIL) {                                                           \
        asm volatile("s_waitcnt vmcnt(" #EW ")" ::: "memory");             \
        __builtin_amdgcn_sched_barrier(0);                                 \
        BARRIER;                                                           \
    }                                                                      \
  }

    // prologue: stage tiles 0,1 (8 loads/thread); vmcnt(4) -> tile0 landed
    STAGEA(Al0, 0)  STAGEB(Bl0, 0)
    STAGEA(Al1, BK) STAGEB(Bl1, BK)
    asm volatile("s_waitcnt vmcnt(4)" ::: "memory");
    BARRIER;

#pragma unroll 1
    for (int t3 = 0; t3 < 30; t3 += 3) {
        const int k2 = (t3 + 2) * BK, k3 = (t3 + 3) * BK, k4 = (t3 + 4) * BK;
        KTILE(Al0, Bl0, Al2, Bl2, k2, true, 4, true)   // tile t3,   stage t3+2
        KTILE(Al1, Bl1, Al0, Bl0, k3, true, 4, true)   // tile t3+1, stage t3+3
        KTILE(Al2, Bl2, Al1, Bl1, k4, true, 4, true)   // tile t3+2, stage t3+4
    }
    // tiles 30 (buf0), 31 (buf1): no staging; tile30 drains to 0 (tile31's
    // loads must land); tile31 skips the trailing wait entirely.
    KTILE(Al0, Bl0, Al2, Bl2, 0, false, 0, true)
    KTILE(Al1, Bl1, Al2, Bl2, 0, false, 0, false)
#undef STAGEA
#undef STAGEB
#undef LDA
#undef LDB
#undef Q16
#undef KTILE

    // epilogue: C/D layout col=lane&15, row=(lane>>4)*4+reg  [m89-verified]
    const int gate = n0 >> 10;          // block-uniform (256 | 1024)
#pragma unroll
    for (int mi = 0; mi < 8; ++mi) {
        const int rowb = m0 + wm + mi * 16 + (lane >> 4) * 4;
#pragma unroll
        for (int nj = 0; nj < 4; ++nj) {
            const int col = n0 + wn + nj * 16 + lr;
            const int d   = col & 1023;
            const float bb = bias[col];
#pragma unroll
            for (int r = 0; r < 4; ++r) {
                float v = acc[mi][nj][r] + bb;
                const int idx = (rowb + r) * DIMV + d;
                if (gate == 0) {
                    gi[idx] = (_Float16)(10.0f * ftanh((v + ibias[d]) * 0.1f));
                } else if (gate == 1) {
                    gf[idx] = -fsoftplus(v);                           // log-forget
                } else if (gate == 2) {
                    go[idx] = (_Float16)fsig(v);                       // sigmoid
                } else {
                    gtz[idx] = (_Float16)ftanh(v);                     // tanh(z)
                }
            }
        }
    }
}

// ---------- chunked scan ----------
// pass1: per (channel, chunk) local scan from identity (m=-1e30): {F=sum f, M, c, n}
__global__ __launch_bounds__(256) void k_scan1(
    const _Float16* __restrict__ gi, const float* __restrict__ gf,
    const _Float16* __restrict__ gtz, float4* __restrict__ sums)
{
    const int ch = blockIdx.x * 256 + threadIdx.x;   // 0..4095
    const int chunk = blockIdx.y;
    const int b = ch >> 10, d = ch & 1023;
    int base = (b * TT + chunk * CL) * DIMV + d;
    float m = -1e30f, c = 0.0f, n = 0.0f, F = 0.0f;
#pragma unroll 4
    for (int t = 0; t < CL; ++t, base += DIMV) {
        const float iv = (float)gi[base];
        const float fv = gf[base];
        const float zv = (float)gtz[base];
        F += fv;
        const float mn = fmaxf(fv + m, iv);
        const float sc = __expf(fv + m - mn);
        const float si = __expf(iv - mn);
        c = sc * c + si * zv;
        n = sc * n + si;
        m = mn;
    }
    sums[chunk * 4096 + ch] = make_float4(F, m, c, n);
}

// pass2: sequential combine over chunks; emit incoming state per chunk
__global__ __launch_bounds__(256) void k_scan2(const float4* __restrict__ sums,
                                               float4* __restrict__ states) {
    const int ch = blockIdx.x * 256 + threadIdx.x;
    float m = -1e30f, c = 0.0f, n = 0.0f;
    for (int chunk = 0; chunk < NCH; ++chunk) {
        states[chunk * 4096 + ch] = make_float4(m, c, n, 0.0f);
        const float4 s = sums[chunk * 4096 + ch];
        const float mn = fmaxf(m + s.x, s.y);
        const float e1 = __expf(m + s.x - mn);
        const float e2 = __expf(s.y - mn);
        c = e1 * c + e2 * s.z;
        n = e1 * n + e2 * s.w;
        m = mn;
    }
}

// pass3: re-scan chunk from incoming state, emit h (fp16) into hbuf
__global__ __launch_bounds__(256) void k_scan3(
    const _Float16* __restrict__ gi, const float* __restrict__ gf,
    const _Float16* __restrict__ go, const _Float16* __restrict__ gtz,
    const float4* __restrict__ states, _Float16* __restrict__ hbuf)
{
    const int ch = blockIdx.x * 256 + threadIdx.x;
    const int chunk = blockIdx.y;
    const int b = ch >> 10, d = ch & 1023;
    int base = (b * TT + chunk * CL) * DIMV + d;
    const float4 st = states[chunk * 4096 + ch];
    float m = st.x, c = st.y, n = st.z;
#pragma unroll 4
    for (int t = 0; t < CL; ++t, base += DIMV) {
        const float iv = (float)gi[base];
        const float fv = gf[base];
        const float ov = (float)go[base];
        const float zv = (float)gtz[base];
        const float mn = fmaxf(fv + m, iv);
        const float sc = __expf(fv + m - mn);
        const float si = __expf(iv - mn);
        c = sc * c + si * zv;
        n = sc * n + si;
        m = mn;
        hbuf[base] = (_Float16)(ov * c / (n + 1e-6f));
    }
}

// ---------- RMSNorm: read h fp16, write fp32 out; one wave per 1024-row ----------
__global__ __launch_bounds__(256) void k_rmsnorm(const _Float16* __restrict__ h,
                                                 const float* __restrict__ scale,
                                                 float* __restrict__ out) {
    const int wid = threadIdx.x >> 6, lane = threadIdx.x & 63;
    const int row = blockIdx.x * 4 + wid;
    const half8* p = (const half8*)(h + (size_t)row * DIMV);  // 128 half8/row
    const float4* sc = (const float4*)scale;
    half8 v0 = p[lane * 2], v1 = p[lane * 2 + 1];             // 16 f16 per lane
    float f[16];
    float ss = 0.0f;
#pragma unroll
    for (int j = 0; j < 8; ++j) { f[j] = (float)v0[j]; f[8 + j] = (float)v1[j]; }
#pragma unroll
    for (int j = 0; j < 16; ++j) ss += f[j] * f[j];
#pragma unroll
    for (int off = 32; off > 0; off >>= 1) ss += __shfl_xor(ss, off, 64);
    const float inv = 1.0f / sqrtf(ss * (1.0f / 1024.0f) + 1e-8f);
    float4* po = (float4*)(out + (size_t)row * DIMV + lane * 16);
#pragma unroll
    for (int q = 0; q < 4; ++q) {
        const float4 s = sc[lane * 4 + q];
        float4 o;
        o.x = f[q * 4 + 0] * inv * s.x;
        o.y = f[q * 4 + 1] * inv * s.y;
        o.z = f[q * 4 + 2] * inv * s.z;
        o.w = f[q * 4 + 3] * inv * s.w;
        po[q] = o;
    }
}

extern "C" void kernel_launch(void* const* d_in, const int* in_sizes, int n_in,
                              void* d_out, int out_size, void* d_ws, size_t ws_size,
                              hipStream_t stream) {
    (void)in_sizes; (void)n_in; (void)out_size; (void)ws_size;
    const float* x     = (const float*)d_in[0];
    const float* W     = (const float*)d_in[1];
    const float* bias  = (const float*)d_in[2];
    const float* ibias = (const float*)d_in[3];
    const float* scale = (const float*)d_in[4];
    float* out = (float*)d_out;

    char* ws = (char*)d_ws;
    size_t off = 0;
    _Float16* Xs = (_Float16*)(ws + off); off += (size_t)MTOT * KK * 2;     //  33.5 MB
    _Float16* Wt = (_Float16*)(ws + off); off += (size_t)NCOL * KK * 2;     //   8.4 MB
    _Float16* gi = (_Float16*)(ws + off); off += (size_t)MTOT * DIMV * 2;   //  33.5 MB
    float*    gf = (float*)(ws + off);    off += (size_t)MTOT * DIMV * 4;   //  67.1 MB
    _Float16* go = (_Float16*)(ws + off); off += (size_t)MTOT * DIMV * 2;   //  33.5 MB
    _Float16* gtz= (_Float16*)(ws + off); off += (size_t)MTOT * DIMV * 2;   //  33.5 MB
    float4* sums   = (float4*)(ws + off); off += (size_t)NCH * 4096 * 16;   //   4.2 MB
    float4* states = (float4*)(ws + off); off += (size_t)NCH * 4096 * 16;   //   4.2 MB
    _Float16* hbuf = Xs;   // Xs is dead after the GEMM; reuse for h (33.5 MB)

    k_cvt_x<<<(MTOT * DIMV) / 256, 256, 0, stream>>>(x, Xs);
    k_cvt_w<<<dim3(NCOL / 32, KK / 32), 256, 0, stream>>>(W, Wt);
    k_gemm_gates<<<dim3(NCOL / BN, MTOT / BM), 512, 0, stream>>>(
        Xs, Wt, bias, ibias, gi, gf, go, gtz);
    k_scan1<<<dim3(16, NCH), 256, 0, stream>>>(gi, gf, gtz, sums);
    k_scan2<<<16, 256, 0, stream>>>(sums, states);
    k_scan3<<<dim3(16, NCH), 256, 0, stream>>>(gi, gf, go, gtz, states, hbuf);
    k_rmsnorm<<<MTOT / 4, 256, 0, stream>>>(hbuf, scale, out);
}